// Round 13
// baseline (66.075 us; speedup 1.0000x reference)
//
#include <hip/hip_runtime.h>
#include <hip/hip_bf16.h>

#define B_ 2
#define H_ 16
#define T_ 2048
#define D_ 64
#define BH (B_*H_)

typedef __attribute__((ext_vector_type(8))) short bf16x8;
typedef __attribute__((ext_vector_type(16))) float f32x16;
typedef __attribute__((ext_vector_type(4))) unsigned int u32x4;
typedef unsigned int u32;

typedef __attribute__((address_space(3))) void lds_void;
typedef __attribute__((address_space(1))) const void gbl_void;

__device__ __forceinline__ ushort f2bu(float x){
    __hip_bfloat16 h = __float2bfloat16(x);
    return __builtin_bit_cast(ushort, h);
}
__device__ __forceinline__ u32 cvtpk(float a, float b){
    u32 r; asm("v_cvt_pk_bf16_f32 %0, %1, %2" : "=v"(r) : "v"(a), "v"(b)); return r;
}
// Cross-half (lane ^ 32) reductions via permlane32_swap. Empty asm on b keeps
// it in its OWN register (round-4 lesson: coalescer self-swap bug -> NaN).
__device__ __forceinline__ float xhalf_max(float x){
    float a = x, b = x;
    asm("" : "+v"(b));
    asm("v_permlane32_swap_b32 %0, %1" : "+v"(a), "+v"(b));
    return fmaxf(a, b);
}
__device__ __forceinline__ float xhalf_sum(float x){
    float a = x, b = x;
    asm("" : "+v"(b));
    asm("v_permlane32_swap_b32 %0, %1" : "+v"(a), "+v"(b));
    return a + b;
}

// Fused prep (bodies verbatim from the rounds-2..12-proven tr_bf16):
//  blockIdx.y < 32: k f32 [D][T] -> KT bf16 [T][D], vmask'd key rows zeroed
//  blockIdx.y >= 32: v f32 [T][D] -> VT bf16 [D][T]
__global__ __launch_bounds__(256) void prep(
    const float* __restrict__ k, const float* __restrict__ v,
    const float* __restrict__ vm,
    ushort* __restrict__ KT, ushort* __restrict__ VT)
{
    __shared__ ushort tl[64][65];
    const int bh = blockIdx.x;
    const bool isK = (blockIdx.y < 32);
    const int ty = isK ? blockIdx.y : (blockIdx.y - 32);
    const int i0 = isK ? 0 : ty*64;
    const int j0 = isK ? ty*64 : 0;
    const int M = isK ? D_ : T_;
    const int N = isK ? T_ : D_;
    const float* s = (isK ? k : v) + (size_t)bh*M*N;
    ushort*      d = (isK ? KT : VT) + (size_t)bh*M*N;
    const int tid = threadIdx.x;
    const int rr = tid>>4, c4 = (tid&15)*4;
    #pragma unroll
    for (int p=0;p<4;++p){
        int a = p*16+rr;
        float4 x = *reinterpret_cast<const float4*>(&s[(size_t)(i0+a)*N + j0 + c4]);
        tl[c4+0][a]=f2bu(x.x); tl[c4+1][a]=f2bu(x.y);
        tl[c4+2][a]=f2bu(x.z); tl[c4+3][a]=f2bu(x.w);
    }
    __syncthreads();
    #pragma unroll
    for (int p=0;p<4;++p){
        int bb = p*16+rr;
        ushort4 u;
        u.x=tl[bb][c4]; u.y=tl[bb][c4+1]; u.z=tl[bb][c4+2]; u.w=tl[bb][c4+3];
        if (isK && vm[(size_t)(bh>>4)*T_ + j0 + bb] == 0.f) { u.x=0;u.y=0;u.z=0;u.w=0; }
        *reinterpret_cast<ushort4*>(&d[(size_t)(j0+bb)*M + i0 + c4]) = u;
    }
}

// Barrier-free flash attention, 64 q-rows per wave (two 32-row halves A/B
// sharing each staged K/V tile). 1024 one-wave blocks = exactly 4/CU (LDS cap
// 5) -> all blocks resident, CU tile-sums exactly 66 via the qw pairing map.
// Double-buffered 32KB LDS, global_load_lds staging with pre-swizzled source
// (R10-12 proven), single vmcnt(0) drain per tile. No barriers anywhere.
__global__ __launch_bounds__(64, 2) void attn_fwd(
    const float* __restrict__ q, const float* __restrict__ fp,
    const float* __restrict__ hmask,
    const ushort* __restrict__ KT,   // bf16 [T][D] per bh (vmask'd rows zeroed)
    const ushort* __restrict__ VT,   // bf16 [D][T] per bh
    float* __restrict__ out)
{
    __shared__ __align__(16) ushort sbuf[2][8192];  // [buf][K:0-4095 | V:4096-8191]

    const int bid = blockIdx.x;
    const int bh = bid & (BH-1);
    const int idx = bid >> 5;                       // 0..31
    const int qw = (bid < 512) ? (31 - idx) : (idx - 16);  // CU-balanced pairs
    const int i0 = qw*64;                           // 64 q-rows per wave
    const int lane = threadIdx.x & 63;
    const int col = lane & 31;
    const int hi  = lane >> 5;

    const ushort* KTb = KT + (size_t)bh*T_*D_;
    const ushort* VTb = VT + (size_t)bh*T_*D_;

    const float sscale = 1.4426950408889634f / fp[0];
    const float hmA = hmask[(size_t)(bh>>4)*T_ + i0 + col];
    const float hmB = hmask[(size_t)(bh>>4)*T_ + i0 + 32 + col];
    const float qsA = (hmA != 0.f) ? sscale : 0.f;
    const float qsB = (hmB != 0.f) ? sscale : 0.f;
    const float NINF = -__builtin_inff();

    // Q B-frags for both halves (R3-12 proven layout)
    bf16x8 qfA[4], qfB[4];
    {
        const float* qpA = q + (size_t)bh*T_*D_ + (size_t)(i0+col)*D_ + hi*8;
        const float* qpB = qpA + 32*D_;
        #pragma unroll
        for (int dc=0; dc<4; ++dc){
            float4 x0 = *reinterpret_cast<const float4*>(qpA + dc*16);
            float4 x1 = *reinterpret_cast<const float4*>(qpA + dc*16 + 4);
            u32x4 dw;
            dw[0] = cvtpk(x0.x*qsA, x0.y*qsA);
            dw[1] = cvtpk(x0.z*qsA, x0.w*qsA);
            dw[2] = cvtpk(x1.x*qsA, x1.y*qsA);
            dw[3] = cvtpk(x1.z*qsA, x1.w*qsA);
            qfA[dc] = __builtin_bit_cast(bf16x8, dw);
            float4 y0 = *reinterpret_cast<const float4*>(qpB + dc*16);
            float4 y1 = *reinterpret_cast<const float4*>(qpB + dc*16 + 4);
            u32x4 ew;
            ew[0] = cvtpk(y0.x*qsB, y0.y*qsB);
            ew[1] = cvtpk(y0.z*qsB, y0.w*qsB);
            ew[2] = cvtpk(y1.x*qsB, y1.y*qsB);
            ew[3] = cvtpk(y1.z*qsB, y1.w*qsB);
            qfB[dc] = __builtin_bit_cast(bf16x8, ew);
        }
    }

    float mA = 0.f, lA = 0.f, mB = 0.f, lB = 0.f;   // defer-max: 0-init is safe
    f32x16 oA0, oA1, oB0, oB1;
    #pragma unroll
    for (int r=0;r<16;++r){ oA0[r]=0.f; oA1[r]=0.f; oB0[r]=0.f; oB1[r]=0.f; }

    const unsigned uoff = (unsigned)(lane*16);
    const unsigned swz = ((unsigned)(col&7)) << 4;

    // stage tile t into buffer b (verbatim R10-12 addressing)
    auto stage = [&](int b, int t){
        char* ldsK = (char*)&sbuf[b][0];
        char* ldsV = (char*)&sbuf[b][4096];
        const char* kbase = (const char*)KTb + (size_t)t*8192;
        #pragma unroll
        for (int i=0;i<8;++i){
            const unsigned u = i*1024u + uoff;
            const unsigned su = u ^ (((u>>7)&7u)<<4);
            __builtin_amdgcn_global_load_lds(
                (gbl_void*)(kbase + su),
                (lds_void*)(ldsK + i*1024), 16, 0, 0);
        }
        #pragma unroll
        for (int i=0;i<8;++i){
            const unsigned u = i*1024u + uoff;
            const unsigned dR = u>>7;
            const unsigned inr = (u&127u) ^ ((dR&7u)<<4);
            const char* src = (const char*)VTb + (size_t)dR*(T_*2) + (size_t)t*128 + inr;
            __builtin_amdgcn_global_load_lds(
                (gbl_void*)src,
                (lds_void*)(ldsV + i*1024), 16, 0, 0);
        }
    };

    const int n = qw + 1;   // tiles cover keys <= i0+63
    int buf = 0;
    stage(0, 0);
    asm volatile("s_waitcnt vmcnt(0)" ::: "memory");

    for (int t=0; t<n; ++t){
        const int j0 = t*64;
        if (t+1 < n) stage(buf^1, t+1);   // prefetch; drained at loop bottom

        // K frags (shared by both halves) — verbatim R10-12
        const char* sKb = (const char*)&sbuf[buf][0];
        bf16x8 kf[8];
        #pragma unroll
        for (int kt=0;kt<2;++kt)
            #pragma unroll
            for (int dc=0;dc<4;++dc)
                kf[kt*4+dc] = *reinterpret_cast<const bf16x8*>(
                    sKb + (((unsigned)(kt*4096 + dc*32 + col*128 + hi*16)) ^ swz));

        f32x16 sA0, sA1, sB0, sB1;
        #pragma unroll
        for (int r=0;r<16;++r){ sA0[r]=0.f; sA1[r]=0.f; sB0[r]=0.f; sB1[r]=0.f; }
        #pragma unroll
        for (int dc=0;dc<4;++dc){
            sA0 = __builtin_amdgcn_mfma_f32_32x32x16_bf16(kf[dc],   qfA[dc], sA0, 0,0,0);
            sA1 = __builtin_amdgcn_mfma_f32_32x32x16_bf16(kf[4+dc], qfA[dc], sA1, 0,0,0);
            sB0 = __builtin_amdgcn_mfma_f32_32x32x16_bf16(kf[dc],   qfB[dc], sB0, 0,0,0);
            sB1 = __builtin_amdgcn_mfma_f32_32x32x16_bf16(kf[4+dc], qfB[dc], sB1, 0,0,0);
        }

        // V frags (shared) — verbatim R10-12
        const char* sVb = (const char*)&sbuf[buf][4096];
        bf16x8 vf[8];
        #pragma unroll
        for (int f=0;f<8;++f)
            vf[f] = *reinterpret_cast<const bf16x8*>(
                sVb + (((unsigned)((f>>2)*4096 + (f&3)*32 + col*128 + hi*16)) ^ swz));

        // causal mask: only the last tile (t == qw) is partial for A and B
        if (j0 + 63 > i0) {
            const int thA0 = i0 + col - j0 - 4*hi,      thA1 = thA0 - 32;
            const int thB0 = i0 + 32 + col - j0 - 4*hi, thB1 = thB0 - 32;
            #pragma unroll
            for (int r=0;r<16;++r){
                const int basr = (r&3) + 8*(r>>2);
                sA0[r] = (basr <= thA0) ? sA0[r] : NINF;
                sA1[r] = (basr <= thA1) ? sA1[r] : NINF;
                sB0[r] = (basr <= thB0) ? sB0[r] : NINF;
                sB1[r] = (basr <= thB1) ? sB1[r] : NINF;
            }
        }

        // ---- half A: softmax + PV ----
        {
            float tm[8];
            #pragma unroll
            for (int i=0;i<8;++i)
                tm[i] = fmaxf(fmaxf(sA0[2*i], sA0[2*i+1]), fmaxf(sA1[2*i], sA1[2*i+1]));
            #pragma unroll
            for (int st=4; st>=1; st>>=1)
                #pragma unroll
                for (int i=0;i<st;++i) tm[i] = fmaxf(tm[i], tm[i+st]);
            const float mt = xhalf_max(tm[0]);
            if (__any(!(mt <= mA + 8.0f))) {          // defer-max (T13)
                const float mn = fmaxf(mA, mt);
                const float fac = __builtin_amdgcn_exp2f(mA - mn);
                mA = mn; lA *= fac;
                #pragma unroll
                for (int r=0;r<16;++r){ oA0[r]*=fac; oA1[r]*=fac; }
            }
            float tsum[8];
            #pragma unroll
            for (int i=0;i<8;++i){
                float p00 = __builtin_amdgcn_exp2f(sA0[2*i]   - mA);
                float p01 = __builtin_amdgcn_exp2f(sA0[2*i+1] - mA);
                float p10 = __builtin_amdgcn_exp2f(sA1[2*i]   - mA);
                float p11 = __builtin_amdgcn_exp2f(sA1[2*i+1] - mA);
                sA0[2*i]=p00; sA0[2*i+1]=p01; sA1[2*i]=p10; sA1[2*i+1]=p11;
                tsum[i] = (p00+p01) + (p10+p11);
            }
            #pragma unroll
            for (int st=4; st>=1; st>>=1)
                #pragma unroll
                for (int i=0;i<st;++i) tsum[i] += tsum[i+st];
            lA += xhalf_sum(tsum[0]);

            bf16x8 pb[4];
            #pragma unroll
            for (int c2=0;c2<4;++c2){
                const f32x16& ps = (c2<2) ? sA0 : sA1;
                const int rb = (c2&1)*8;
                u32 a0 = cvtpk(ps[rb+0], ps[rb+1]);
                u32 a1 = cvtpk(ps[rb+2], ps[rb+3]);
                u32 a2 = cvtpk(ps[rb+4], ps[rb+5]);
                u32 a3 = cvtpk(ps[rb+6], ps[rb+7]);
                asm("v_permlane32_swap_b32 %0, %1" : "+v"(a0), "+v"(a2));
                asm("v_permlane32_swap_b32 %0, %1" : "+v"(a1), "+v"(a3));
                u32x4 dw; dw[0]=a0; dw[1]=a1; dw[2]=a2; dw[3]=a3;
                pb[c2] = __builtin_bit_cast(bf16x8, dw);
            }
            #pragma unroll
            for (int c2=0;c2<4;++c2){
                oA0 = __builtin_amdgcn_mfma_f32_32x32x16_bf16(vf[c2],   pb[c2], oA0, 0,0,0);
                oA1 = __builtin_amdgcn_mfma_f32_32x32x16_bf16(vf[4+c2], pb[c2], oA1, 0,0,0);
            }
        }

        // ---- half B: softmax + PV (VALU overlaps half-A PV MFMAs) ----
        {
            float tm[8];
            #pragma unroll
            for (int i=0;i<8;++i)
                tm[i] = fmaxf(fmaxf(sB0[2*i], sB0[2*i+1]), fmaxf(sB1[2*i], sB1[2*i+1]));
            #pragma unroll
            for (int st=4; st>=1; st>>=1)
                #pragma unroll
                for (int i=0;i<st;++i) tm[i] = fmaxf(tm[i], tm[i+st]);
            const float mt = xhalf_max(tm[0]);
            if (__any(!(mt <= mB + 8.0f))) {
                const float mn = fmaxf(mB, mt);
                const float fac = __builtin_amdgcn_exp2f(mB - mn);
                mB = mn; lB *= fac;
                #pragma unroll
                for (int r=0;r<16;++r){ oB0[r]*=fac; oB1[r]*=fac; }
            }
            float tsum[8];
            #pragma unroll
            for (int i=0;i<8;++i){
                float p00 = __builtin_amdgcn_exp2f(sB0[2*i]   - mB);
                float p01 = __builtin_amdgcn_exp2f(sB0[2*i+1] - mB);
                float p10 = __builtin_amdgcn_exp2f(sB1[2*i]   - mB);
                float p11 = __builtin_amdgcn_exp2f(sB1[2*i+1] - mB);
                sB0[2*i]=p00; sB0[2*i+1]=p01; sB1[2*i]=p10; sB1[2*i+1]=p11;
                tsum[i] = (p00+p01) + (p10+p11);
            }
            #pragma unroll
            for (int st=4; st>=1; st>>=1)
                #pragma unroll
                for (int i=0;i<st;++i) tsum[i] += tsum[i+st];
            lB += xhalf_sum(tsum[0]);

            bf16x8 pb[4];
            #pragma unroll
            for (int c2=0;c2<4;++c2){
                const f32x16& ps = (c2<2) ? sB0 : sB1;
                const int rb = (c2&1)*8;
                u32 a0 = cvtpk(ps[rb+0], ps[rb+1]);
                u32 a1 = cvtpk(ps[rb+2], ps[rb+3]);
                u32 a2 = cvtpk(ps[rb+4], ps[rb+5]);
                u32 a3 = cvtpk(ps[rb+6], ps[rb+7]);
                asm("v_permlane32_swap_b32 %0, %1" : "+v"(a0), "+v"(a2));
                asm("v_permlane32_swap_b32 %0, %1" : "+v"(a1), "+v"(a3));
                u32x4 dw; dw[0]=a0; dw[1]=a1; dw[2]=a2; dw[3]=a3;
                pb[c2] = __builtin_bit_cast(bf16x8, dw);
            }
            #pragma unroll
            for (int c2=0;c2<4;++c2){
                oB0 = __builtin_amdgcn_mfma_f32_32x32x16_bf16(vf[c2],   pb[c2], oB0, 0,0,0);
                oB1 = __builtin_amdgcn_mfma_f32_32x32x16_bf16(vf[4+c2], pb[c2], oB1, 0,0,0);
            }
        }

        asm volatile("s_waitcnt vmcnt(0)" ::: "memory");  // next tile landed
        buf ^= 1;
    }

    // epilogue: O = O^T / l, float4 stores (both halves)
    {
        const float riA = 1.0f / lA;
        float* opA = out + (size_t)bh*T_*D_ + (size_t)(i0+col)*D_;
        const float riB = 1.0f / lB;
        float* opB = opA + 32*D_;
        #pragma unroll
        for (int q4=0;q4<4;++q4){
            float4 a = {oA0[4*q4]*riA, oA0[4*q4+1]*riA, oA0[4*q4+2]*riA, oA0[4*q4+3]*riA};
            *reinterpret_cast<float4*>(opA + 8*q4 + 4*hi) = a;
            float4 b = {oA1[4*q4]*riA, oA1[4*q4+1]*riA, oA1[4*q4+2]*riA, oA1[4*q4+3]*riA};
            *reinterpret_cast<float4*>(opA + 32 + 8*q4 + 4*hi) = b;
            float4 c = {oB0[4*q4]*riB, oB0[4*q4+1]*riB, oB0[4*q4+2]*riB, oB0[4*q4+3]*riB};
            *reinterpret_cast<float4*>(opB + 8*q4 + 4*hi) = c;
            float4 d = {oB1[4*q4]*riB, oB1[4*q4+1]*riB, oB1[4*q4+2]*riB, oB1[4*q4+3]*riB};
            *reinterpret_cast<float4*>(opB + 32 + 8*q4 + 4*hi) = d;
        }
    }
}

extern "C" void kernel_launch(void* const* d_in, const int* in_sizes, int n_in,
                              void* d_out, int out_size, void* d_ws, size_t ws_size,
                              hipStream_t stream) {
    const float* q  = (const float*)d_in[0];
    const float* k  = (const float*)d_in[1];
    const float* v  = (const float*)d_in[2];
    const float* f  = (const float*)d_in[3];
    const float* vm = (const float*)d_in[4];
    const float* hm = (const float*)d_in[5];
    float* out = (float*)d_out;

    const size_t slab = (size_t)BH * T_ * D_;
    ushort* KT = (ushort*)d_ws;
    ushort* VT = KT + slab;

    // fused K+V prep (proven bodies, one launch)
    hipLaunchKernelGGL(prep, dim3(BH, 64), dim3(256), 0, stream, k, v, vm, KT, VT);

    dim3 grid(1024);   // 32 bh x 32 q-blocks of 64 rows; all blocks resident
    dim3 block(64);
    hipLaunchKernelGGL(attn_fwd, grid, block, 0, stream, q, f, hm, KT, VT, out);
}

// Round 14
// 53.743 us; speedup vs baseline: 1.2295x; 1.2295x over previous
//
#include <hip/hip_runtime.h>
#include <hip/hip_bf16.h>

#define B_ 2
#define H_ 16
#define T_ 2048
#define D_ 64
#define BH (B_*H_)

typedef __attribute__((ext_vector_type(8))) short bf16x8;
typedef __attribute__((ext_vector_type(16))) float f32x16;
typedef __attribute__((ext_vector_type(4))) unsigned int u32x4;
typedef unsigned int u32;

typedef __attribute__((address_space(3))) void lds_void;
typedef __attribute__((address_space(1))) const void gbl_void;

__device__ __forceinline__ ushort f2bu(float x){
    __hip_bfloat16 h = __float2bfloat16(x);
    return __builtin_bit_cast(ushort, h);
}
__device__ __forceinline__ u32 cvtpk(float a, float b){
    u32 r; asm("v_cvt_pk_bf16_f32 %0, %1, %2" : "=v"(r) : "v"(a), "v"(b)); return r;
}
// Cross-half (lane ^ 32) reductions via permlane32_swap. Empty asm on b keeps
// it in its OWN register (round-4 lesson: coalescer self-swap bug -> NaN).
__device__ __forceinline__ float xhalf_max(float x){
    float a = x, b = x;
    asm("" : "+v"(b));
    asm("v_permlane32_swap_b32 %0, %1" : "+v"(a), "+v"(b));
    return fmaxf(a, b);
}
__device__ __forceinline__ float xhalf_sum(float x){
    float a = x, b = x;
    asm("" : "+v"(b));
    asm("v_permlane32_swap_b32 %0, %1" : "+v"(a), "+v"(b));
    return a + b;
}

// Fused prep (bodies verbatim from the rounds-2..13-proven tr_bf16):
//  blockIdx.y < 32: k f32 [D][T] -> KT bf16 [T][D], vmask'd key rows zeroed
//  blockIdx.y >= 32: v f32 [T][D] -> VT bf16 [D][T]
__global__ __launch_bounds__(256) void prep(
    const float* __restrict__ k, const float* __restrict__ v,
    const float* __restrict__ vm,
    ushort* __restrict__ KT, ushort* __restrict__ VT)
{
    __shared__ ushort tl[64][65];
    const int bh = blockIdx.x;
    const bool isK = (blockIdx.y < 32);
    const int ty = isK ? blockIdx.y : (blockIdx.y - 32);
    const int i0 = isK ? 0 : ty*64;
    const int j0 = isK ? ty*64 : 0;
    const int M = isK ? D_ : T_;
    const int N = isK ? T_ : D_;
    const float* s = (isK ? k : v) + (size_t)bh*M*N;
    ushort*      d = (isK ? KT : VT) + (size_t)bh*M*N;
    const int tid = threadIdx.x;
    const int rr = tid>>4, c4 = (tid&15)*4;
    #pragma unroll
    for (int p=0;p<4;++p){
        int a = p*16+rr;
        float4 x = *reinterpret_cast<const float4*>(&s[(size_t)(i0+a)*N + j0 + c4]);
        tl[c4+0][a]=f2bu(x.x); tl[c4+1][a]=f2bu(x.y);
        tl[c4+2][a]=f2bu(x.z); tl[c4+3][a]=f2bu(x.w);
    }
    __syncthreads();
    #pragma unroll
    for (int p=0;p<4;++p){
        int bb = p*16+rr;
        ushort4 u;
        u.x=tl[bb][c4]; u.y=tl[bb][c4+1]; u.z=tl[bb][c4+2]; u.w=tl[bb][c4+3];
        if (isK && vm[(size_t)(bh>>4)*T_ + j0 + bb] == 0.f) { u.x=0;u.y=0;u.z=0;u.w=0; }
        *reinterpret_cast<ushort4*>(&d[(size_t)(j0+bb)*M + i0 + c4]) = u;
    }
}

// Critical-path-minimal flash attention: 256 blocks (ONE per CU), 4 waves
// sharing double-buffered 32KB K/V tiles. Each block processes TWO q-panels
// (qb = 15-pr, then pr) sequentially -> EVERY block runs exactly 36
// tile-steps: zero tail, zero queue, uniform finish. Staging = R10-proven
// global_load_lds w16 w/ pre-swizzled source, split 4KB/wave. Buffer protocol
// = R11-proven syncthreads-drain double-buffer (1 barrier per tile). Compute
// = R12-proven (no-mask trick, defer-max, tree reduce, cvtpk+permlane).
__global__ __launch_bounds__(256, 2) void attn_fwd(
    const float* __restrict__ q, const float* __restrict__ fp,
    const float* __restrict__ hmask,
    const ushort* __restrict__ KT,   // bf16 [T][D] per bh (vmask'd rows zeroed)
    const ushort* __restrict__ VT,   // bf16 [D][T] per bh
    float* __restrict__ out)
{
    __shared__ __align__(16) ushort sbuf[2][8192];  // [buf][K:0-4095 | V:4096-8191]

    const int bid = blockIdx.x;
    const int bh = bid & (BH-1);
    const int pr = bid >> 5;                        // 0..7: panel pair id
    const int tid = threadIdx.x;
    const int lane = tid & 63;
    const int wid  = tid >> 6;                      // 0..3
    const int col = lane & 31;
    const int hi  = lane >> 5;

    const ushort* KTb = KT + (size_t)bh*T_*D_;
    const ushort* VTb = VT + (size_t)bh*T_*D_;
    const float sscale = 1.4426950408889634f / fp[0];
    const float NINF = -__builtin_inff();

    const unsigned uoff = (unsigned)(wid*1024 + lane*16);  // staging cursor
    const unsigned swz = ((unsigned)(col&7)) << 4;         // frag-read swizzle

    // stage tile t into buffer b (verbatim R10 addressing, 4KB per wave)
    auto stage = [&](int b, int t){
        char* ldsK = (char*)&sbuf[b][0];
        char* ldsV = (char*)&sbuf[b][4096];
        const char* kbase = (const char*)KTb + (size_t)t*8192;
        #pragma unroll
        for (int i=0;i<2;++i){
            const unsigned u = i*4096u + uoff;
            const unsigned su = u ^ (((u>>7)&7u)<<4);
            __builtin_amdgcn_global_load_lds(
                (gbl_void*)(kbase + su),
                (lds_void*)(ldsK + i*4096 + wid*1024), 16, 0, 0);
        }
        #pragma unroll
        for (int i=0;i<2;++i){
            const unsigned u = i*4096u + uoff;
            const unsigned dR = u>>7;
            const unsigned inr = (u&127u) ^ ((dR&7u)<<4);
            const char* src = (const char*)VTb + (size_t)dR*(T_*2) + (size_t)t*128 + inr;
            __builtin_amdgcn_global_load_lds(
                (gbl_void*)src,
                (lds_void*)(ldsV + i*4096 + wid*1024), 16, 0, 0);
        }
    };

    #pragma unroll 1
    for (int pp=0; pp<2; ++pp){
        const int qb = pp ? pr : (15 - pr);         // heavy panel first
        const int i0w = qb*128 + wid*32;            // this wave's 32 q-rows

        const float hmv = hmask[(size_t)(bh>>4)*T_ + i0w + col];
        const float qs = (hmv != 0.f) ? sscale : 0.f;

        // Q B-frags (pre-scaled, R3-13 proven layout)
        bf16x8 qf[4];
        {
            const float* qp = q + (size_t)bh*T_*D_ + (size_t)(i0w+col)*D_ + hi*8;
            #pragma unroll
            for (int dc=0; dc<4; ++dc){
                float4 x0 = *reinterpret_cast<const float4*>(qp + dc*16);
                float4 x1 = *reinterpret_cast<const float4*>(qp + dc*16 + 4);
                u32x4 dw;
                dw[0] = cvtpk(x0.x*qs, x0.y*qs);
                dw[1] = cvtpk(x0.z*qs, x0.w*qs);
                dw[2] = cvtpk(x1.x*qs, x1.y*qs);
                dw[3] = cvtpk(x1.z*qs, x1.w*qs);
                qf[dc] = __builtin_bit_cast(bf16x8, dw);
            }
        }

        float m_run = 0.f, l_run = 0.f;             // defer-max: 0-init safe
        f32x16 o0, o1;
        #pragma unroll
        for (int r=0;r<16;++r){ o0[r]=0.f; o1[r]=0.f; }

        const int n = 2*qb + 2;                     // tiles cover keys <= qb*128+127
        int bsel = 0;
        __syncthreads();                            // prev panel fully done
        stage(0, 0);

        for (int it=0; it<n; ++it){
            const int j0 = it*64;
            __syncthreads();      // drains stage(it) block-wide; compute(it-1) done
            if (it+1 < n) stage(bsel^1, it+1);

            if (j0 <= i0w + 31){
                // K frags (verbatim R10-12)
                const char* sKb = (const char*)&sbuf[bsel][0];
                bf16x8 kf[8];
                #pragma unroll
                for (int kt=0;kt<2;++kt)
                    #pragma unroll
                    for (int dc=0;dc<4;++dc)
                        kf[kt*4+dc] = *reinterpret_cast<const bf16x8*>(
                            sKb + (((unsigned)(kt*4096 + dc*32 + col*128 + hi*16)) ^ swz));

                f32x16 s0, s1;
                #pragma unroll
                for (int r=0;r<16;++r){ s0[r]=0.f; s1[r]=0.f; }
                #pragma unroll
                for (int dc=0;dc<4;++dc){
                    s0 = __builtin_amdgcn_mfma_f32_32x32x16_bf16(kf[dc],   qf[dc], s0, 0,0,0);
                    s1 = __builtin_amdgcn_mfma_f32_32x32x16_bf16(kf[4+dc], qf[dc], s1, 0,0,0);
                }

                // V frags (verbatim R10-12)
                const char* sVb = (const char*)&sbuf[bsel][4096];
                bf16x8 vf[8];
                #pragma unroll
                for (int f=0;f<8;++f)
                    vf[f] = *reinterpret_cast<const bf16x8*>(
                        sVb + (((unsigned)((f>>2)*4096 + (f&3)*32 + col*128 + hi*16)) ^ swz));

                // causal -inf (diagonal tiles only). masked_fill(s==0,1e-10) is a
                // numeric no-op in fp32 (R12-proven): masked scores are exactly 0.
                if (j0 + 63 > i0w) {
                    const int th0 = i0w + col - j0 - 4*hi;
                    const int th1 = th0 - 32;
                    #pragma unroll
                    for (int r=0;r<16;++r){
                        const int basr = (r&3) + 8*(r>>2);
                        s0[r] = (basr <= th0) ? s0[r] : NINF;
                        s1[r] = (basr <= th1) ? s1[r] : NINF;
                    }
                }

                // row max (tree + cross-half), defer-max rescale (R12-proven)
                float tm[8];
                #pragma unroll
                for (int i=0;i<8;++i)
                    tm[i] = fmaxf(fmaxf(s0[2*i], s0[2*i+1]), fmaxf(s1[2*i], s1[2*i+1]));
                #pragma unroll
                for (int st=4; st>=1; st>>=1)
                    #pragma unroll
                    for (int i=0;i<st;++i) tm[i] = fmaxf(tm[i], tm[i+st]);
                const float mt = xhalf_max(tm[0]);
                if (__any(!(mt <= m_run + 8.0f))) {
                    const float mn = fmaxf(m_run, mt);
                    const float fac = __builtin_amdgcn_exp2f(m_run - mn);
                    m_run = mn; l_run *= fac;
                    #pragma unroll
                    for (int r=0;r<16;++r){ o0[r]*=fac; o1[r]*=fac; }
                }

                float tsum[8];
                #pragma unroll
                for (int i=0;i<8;++i){
                    float p00 = __builtin_amdgcn_exp2f(s0[2*i]   - m_run);
                    float p01 = __builtin_amdgcn_exp2f(s0[2*i+1] - m_run);
                    float p10 = __builtin_amdgcn_exp2f(s1[2*i]   - m_run);
                    float p11 = __builtin_amdgcn_exp2f(s1[2*i+1] - m_run);
                    s0[2*i]=p00; s0[2*i+1]=p01; s1[2*i]=p10; s1[2*i+1]=p11;
                    tsum[i] = (p00+p01) + (p10+p11);
                }
                #pragma unroll
                for (int st=4; st>=1; st>>=1)
                    #pragma unroll
                    for (int i=0;i<st;++i) tsum[i] += tsum[i+st];
                l_run += xhalf_sum(tsum[0]);

                // P -> bf16 B-frags (R3-13 proven)
                bf16x8 pb[4];
                #pragma unroll
                for (int c2=0;c2<4;++c2){
                    const f32x16& ps = (c2<2) ? s0 : s1;
                    const int rb = (c2&1)*8;
                    u32 a0 = cvtpk(ps[rb+0], ps[rb+1]);
                    u32 a1 = cvtpk(ps[rb+2], ps[rb+3]);
                    u32 a2 = cvtpk(ps[rb+4], ps[rb+5]);
                    u32 a3 = cvtpk(ps[rb+6], ps[rb+7]);
                    asm("v_permlane32_swap_b32 %0, %1" : "+v"(a0), "+v"(a2));
                    asm("v_permlane32_swap_b32 %0, %1" : "+v"(a1), "+v"(a3));
                    u32x4 dw; dw[0]=a0; dw[1]=a1; dw[2]=a2; dw[3]=a3;
                    pb[c2] = __builtin_bit_cast(bf16x8, dw);
                }

                // O^T += V^T P^T
                #pragma unroll
                for (int c2=0;c2<4;++c2){
                    o0 = __builtin_amdgcn_mfma_f32_32x32x16_bf16(vf[c2],   pb[c2], o0, 0,0,0);
                    o1 = __builtin_amdgcn_mfma_f32_32x32x16_bf16(vf[4+c2], pb[c2], o1, 0,0,0);
                }
            }
            bsel ^= 1;
        }

        // epilogue: O = O^T / l, float4 stores (no LDS use -> no extra barrier)
        const float rinv = 1.0f / l_run;
        float* op = out + (size_t)bh*T_*D_ + (size_t)(i0w+col)*D_;
        #pragma unroll
        for (int q4=0;q4<4;++q4){
            float4 a = {o0[4*q4]*rinv, o0[4*q4+1]*rinv, o0[4*q4+2]*rinv, o0[4*q4+3]*rinv};
            *reinterpret_cast<float4*>(op + 8*q4 + 4*hi) = a;
            float4 b = {o1[4*q4]*rinv, o1[4*q4+1]*rinv, o1[4*q4+2]*rinv, o1[4*q4+3]*rinv};
            *reinterpret_cast<float4*>(op + 32 + 8*q4 + 4*hi) = b;
        }
    }
}

extern "C" void kernel_launch(void* const* d_in, const int* in_sizes, int n_in,
                              void* d_out, int out_size, void* d_ws, size_t ws_size,
                              hipStream_t stream) {
    const float* q  = (const float*)d_in[0];
    const float* k  = (const float*)d_in[1];
    const float* v  = (const float*)d_in[2];
    const float* f  = (const float*)d_in[3];
    const float* vm = (const float*)d_in[4];
    const float* hm = (const float*)d_in[5];
    float* out = (float*)d_out;

    const size_t slab = (size_t)BH * T_ * D_;
    ushort* KT = (ushort*)d_ws;
    ushort* VT = KT + slab;

    // fused K+V prep (proven bodies, one launch)
    hipLaunchKernelGGL(prep, dim3(BH, 64), dim3(256), 0, stream, k, v, vm, KT, VT);

    dim3 grid(256);    // one block per CU; each does panels (15-pr) then pr
    dim3 block(256);   // 4 waves sharing double-buffered tiles
    hipLaunchKernelGGL(attn_fwd, grid, block, 0, stream, q, f, hm, KT, VT, out);
}

// Round 15
// 51.515 us; speedup vs baseline: 1.2826x; 1.0433x over previous
//
#include <hip/hip_runtime.h>
#include <hip/hip_bf16.h>

#define B_ 2
#define H_ 16
#define T_ 2048
#define D_ 64
#define BH (B_*H_)

typedef __attribute__((ext_vector_type(8))) short bf16x8;
typedef __attribute__((ext_vector_type(16))) float f32x16;
typedef __attribute__((ext_vector_type(4))) unsigned int u32x4;
typedef unsigned int u32;

typedef __attribute__((address_space(3))) void lds_void;
typedef __attribute__((address_space(1))) const void gbl_void;

__device__ __forceinline__ ushort f2bu(float x){
    __hip_bfloat16 h = __float2bfloat16(x);
    return __builtin_bit_cast(ushort, h);
}
__device__ __forceinline__ u32 cvtpk(float a, float b){
    u32 r; asm("v_cvt_pk_bf16_f32 %0, %1, %2" : "=v"(r) : "v"(a), "v"(b)); return r;
}
// Cross-half (lane ^ 32) reductions via permlane32_swap. Empty asm on b keeps
// it in its OWN register (round-4 lesson: coalescer self-swap bug -> NaN).
__device__ __forceinline__ float xhalf_max(float x){
    float a = x, b = x;
    asm("" : "+v"(b));
    asm("v_permlane32_swap_b32 %0, %1" : "+v"(a), "+v"(b));
    return fmaxf(a, b);
}
__device__ __forceinline__ float xhalf_sum(float x){
    float a = x, b = x;
    asm("" : "+v"(b));
    asm("v_permlane32_swap_b32 %0, %1" : "+v"(a), "+v"(b));
    return a + b;
}

// Fused prep (bodies verbatim from the rounds-2..14-proven tr_bf16):
//  blockIdx.y < 32: k f32 [D][T] -> KT bf16 [T][D], vmask'd key rows zeroed
//  blockIdx.y >= 32: v f32 [T][D] -> VT bf16 [D][T]
__global__ __launch_bounds__(256) void prep(
    const float* __restrict__ k, const float* __restrict__ v,
    const float* __restrict__ vm,
    ushort* __restrict__ KT, ushort* __restrict__ VT)
{
    __shared__ ushort tl[64][65];
    const int bh = blockIdx.x;
    const bool isK = (blockIdx.y < 32);
    const int ty = isK ? blockIdx.y : (blockIdx.y - 32);
    const int i0 = isK ? 0 : ty*64;
    const int j0 = isK ? ty*64 : 0;
    const int M = isK ? D_ : T_;
    const int N = isK ? T_ : D_;
    const float* s = (isK ? k : v) + (size_t)bh*M*N;
    ushort*      d = (isK ? KT : VT) + (size_t)bh*M*N;
    const int tid = threadIdx.x;
    const int rr = tid>>4, c4 = (tid&15)*4;
    #pragma unroll
    for (int p=0;p<4;++p){
        int a = p*16+rr;
        float4 x = *reinterpret_cast<const float4*>(&s[(size_t)(i0+a)*N + j0 + c4]);
        tl[c4+0][a]=f2bu(x.x); tl[c4+1][a]=f2bu(x.y);
        tl[c4+2][a]=f2bu(x.z); tl[c4+3][a]=f2bu(x.w);
    }
    __syncthreads();
    #pragma unroll
    for (int p=0;p<4;++p){
        int bb = p*16+rr;
        ushort4 u;
        u.x=tl[bb][c4]; u.y=tl[bb][c4+1]; u.z=tl[bb][c4+2]; u.w=tl[bb][c4+3];
        if (isK && vm[(size_t)(bh>>4)*T_ + j0 + bb] == 0.f) { u.x=0;u.y=0;u.z=0;u.w=0; }
        *reinterpret_cast<ushort4*>(&d[(size_t)(j0+bb)*M + i0 + c4]) = u;
    }
}

// Barrier-free flash attention, TLP-first: 2048 one-wave blocks (32 q-rows),
// SINGLE 16KB LDS buffer -> 8 blocks/CU resident (2 independent waves/SIMD,
// MFMA/VALU/trans pipes overlap ACROSS waves). Prefetch preserved despite
// single buffer via reg-staging: K+V frags LDS->regs, lgkmcnt(0)+
// sched_barrier(0) (rule #18), THEN stage(t+1) into the same buffer, then
// compute entirely from registers. vmcnt(0) at loop bottom.
__global__ __launch_bounds__(64, 2) void attn_fwd(
    const float* __restrict__ q, const float* __restrict__ fp,
    const float* __restrict__ hmask,
    const ushort* __restrict__ KT,   // bf16 [T][D] per bh (vmask'd rows zeroed)
    const ushort* __restrict__ VT,   // bf16 [D][T] per bh
    float* __restrict__ out)
{
    __shared__ __align__(16) ushort sbuf[8192];  // K:0-4095 | V:4096-8191

    const int bid = blockIdx.x;
    const int bh = bid & (BH-1);
    const int qw = 63 - (bid >> 5);            // heavy-first, 32 rows per wave
    const int i0 = qw*32;
    const int lane = threadIdx.x & 63;
    const int col = lane & 31;
    const int hi  = lane >> 5;

    const ushort* KTb = KT + (size_t)bh*T_*D_;
    const ushort* VTb = VT + (size_t)bh*T_*D_;

    const float hmv = hmask[(size_t)(bh>>4)*T_ + i0 + col];
    const float sscale = 1.4426950408889634f / fp[0];
    const float qs = (hmv != 0.f) ? sscale : 0.f;   // hmask==0 -> row scores 0
    const float NINF = -__builtin_inff();

    // Q B-frags (pre-scaled): B[d = dc*16+hi*8+e][col]   (rounds 3-14 proven)
    const float* qp = q + (size_t)bh*T_*D_ + (size_t)(i0+col)*D_ + hi*8;
    bf16x8 qf[4];
    #pragma unroll
    for (int dc=0; dc<4; ++dc){
        float4 x0 = *reinterpret_cast<const float4*>(qp + dc*16);
        float4 x1 = *reinterpret_cast<const float4*>(qp + dc*16 + 4);
        u32x4 dw;
        dw[0] = cvtpk(x0.x*qs, x0.y*qs);
        dw[1] = cvtpk(x0.z*qs, x0.w*qs);
        dw[2] = cvtpk(x1.x*qs, x1.y*qs);
        dw[3] = cvtpk(x1.z*qs, x1.w*qs);
        qf[dc] = __builtin_bit_cast(bf16x8, dw);
    }

    float m_run = 0.f, l_run = 0.f;   // defer-max: 0-init safe (R12-14 proven)
    f32x16 o0, o1;
    #pragma unroll
    for (int r=0;r<16;++r){ o0[r]=0.f; o1[r]=0.f; }

    const unsigned uoff = (unsigned)(lane*16);       // staging byte cursor
    const unsigned swz = ((unsigned)(col&7)) << 4;   // frag-read swizzle

    // stage tile t into THE buffer (R10-14-proven addressing, 16 x 1KB loads)
    auto stage = [&](int t){
        char* ldsK = (char*)&sbuf[0];
        char* ldsV = (char*)&sbuf[4096];
        const char* kbase = (const char*)KTb + (size_t)t*8192;
        #pragma unroll
        for (int i=0;i<8;++i){
            const unsigned u = i*1024u + uoff;
            const unsigned su = u ^ (((u>>7)&7u)<<4);
            __builtin_amdgcn_global_load_lds(
                (gbl_void*)(kbase + su),
                (lds_void*)(ldsK + i*1024), 16, 0, 0);
        }
        #pragma unroll
        for (int i=0;i<8;++i){
            const unsigned u = i*1024u + uoff;
            const unsigned dR = u>>7;
            const unsigned inr = (u&127u) ^ ((dR&7u)<<4);
            const char* src = (const char*)VTb + (size_t)dR*(T_*2) + (size_t)t*128 + inr;
            __builtin_amdgcn_global_load_lds(
                (gbl_void*)src,
                (lds_void*)(ldsV + i*1024), 16, 0, 0);
        }
    };

    const int n = (qw >> 1) + 1;     // tiles 0..n-1 cover keys <= i0+31
    stage(0);
    asm volatile("s_waitcnt vmcnt(0)" ::: "memory");

    for (int t=0; t<n; ++t){
        const int j0 = t*64;

        // K+V frags LDS -> registers (R10-14-proven addressing)
        const char* sKb = (const char*)&sbuf[0];
        bf16x8 kf[8];
        #pragma unroll
        for (int kt=0;kt<2;++kt)
            #pragma unroll
            for (int dc=0;dc<4;++dc)
                kf[kt*4+dc] = *reinterpret_cast<const bf16x8*>(
                    sKb + (((unsigned)(kt*4096 + dc*32 + col*128 + hi*16)) ^ swz));
        const char* sVb = (const char*)&sbuf[4096];
        bf16x8 vf[8];
        #pragma unroll
        for (int f=0;f<8;++f)
            vf[f] = *reinterpret_cast<const bf16x8*>(
                sVb + (((unsigned)((f>>2)*4096 + (f&3)*32 + col*128 + hi*16)) ^ swz));

        // all LDS reads complete -> safe to overwrite buffer with next tile.
        // rule #18: sched_barrier(0) stops hipcc hoisting reg-only ops past
        // the inline-asm lgkmcnt.
        asm volatile("s_waitcnt lgkmcnt(0)" ::: "memory");
        __builtin_amdgcn_sched_barrier(0);
        if (t+1 < n) stage(t+1);   // DMA latency hides under compute below

        // S^T = K Q^T
        f32x16 s0, s1;
        #pragma unroll
        for (int r=0;r<16;++r){ s0[r]=0.f; s1[r]=0.f; }
        #pragma unroll
        for (int dc=0;dc<4;++dc){
            s0 = __builtin_amdgcn_mfma_f32_32x32x16_bf16(kf[dc],   qf[dc], s0, 0,0,0);
            s1 = __builtin_amdgcn_mfma_f32_32x32x16_bf16(kf[4+dc], qf[dc], s1, 0,0,0);
        }

        // causal -inf only on the diagonal tile. masked_fill(s==0,1e-10) is a
        // numeric no-op in fp32 (R12-proven): masked scores are exactly 0.
        if (j0 + 63 > i0) {
            const int th0 = i0 + col - j0 - 4*hi;
            const int th1 = th0 - 32;
            #pragma unroll
            for (int r=0;r<16;++r){
                const int basr = (r&3) + 8*(r>>2);
                s0[r] = (basr <= th0) ? s0[r] : NINF;
                s1[r] = (basr <= th1) ? s1[r] : NINF;
            }
        }

        // row max (tree + cross-half), defer-max rescale (R12-14 proven)
        float tm[8];
        #pragma unroll
        for (int i=0;i<8;++i)
            tm[i] = fmaxf(fmaxf(s0[2*i], s0[2*i+1]), fmaxf(s1[2*i], s1[2*i+1]));
        #pragma unroll
        for (int st=4; st>=1; st>>=1)
            #pragma unroll
            for (int i=0;i<st;++i) tm[i] = fmaxf(tm[i], tm[i+st]);
        const float mt = xhalf_max(tm[0]);
        if (__any(!(mt <= m_run + 8.0f))) {
            const float mn = fmaxf(m_run, mt);
            const float fac = __builtin_amdgcn_exp2f(m_run - mn);
            m_run = mn; l_run *= fac;
            #pragma unroll
            for (int r=0;r<16;++r){ o0[r]*=fac; o1[r]*=fac; }
        }

        // P = exp2(s - m_run), row-sum via tree + cross-half
        float tsum[8];
        #pragma unroll
        for (int i=0;i<8;++i){
            float p00 = __builtin_amdgcn_exp2f(s0[2*i]   - m_run);
            float p01 = __builtin_amdgcn_exp2f(s0[2*i+1] - m_run);
            float p10 = __builtin_amdgcn_exp2f(s1[2*i]   - m_run);
            float p11 = __builtin_amdgcn_exp2f(s1[2*i+1] - m_run);
            s0[2*i]=p00; s0[2*i+1]=p01; s1[2*i]=p10; s1[2*i+1]=p11;
            tsum[i] = (p00+p01) + (p10+p11);
        }
        #pragma unroll
        for (int st=4; st>=1; st>>=1)
            #pragma unroll
            for (int i=0;i<st;++i) tsum[i] += tsum[i+st];
        l_run += xhalf_sum(tsum[0]);

        // P -> bf16 B-frags (rounds 3-14 proven)
        bf16x8 pb[4];
        #pragma unroll
        for (int c2=0;c2<4;++c2){
            const f32x16& ps = (c2<2) ? s0 : s1;
            const int rb = (c2&1)*8;
            u32 a0 = cvtpk(ps[rb+0], ps[rb+1]);
            u32 a1 = cvtpk(ps[rb+2], ps[rb+3]);
            u32 a2 = cvtpk(ps[rb+4], ps[rb+5]);
            u32 a3 = cvtpk(ps[rb+6], ps[rb+7]);
            asm("v_permlane32_swap_b32 %0, %1" : "+v"(a0), "+v"(a2));
            asm("v_permlane32_swap_b32 %0, %1" : "+v"(a1), "+v"(a3));
            u32x4 dw; dw[0]=a0; dw[1]=a1; dw[2]=a2; dw[3]=a3;
            pb[c2] = __builtin_bit_cast(bf16x8, dw);
        }

        // O^T += V^T P^T  (all operands in registers)
        #pragma unroll
        for (int c2=0;c2<4;++c2){
            o0 = __builtin_amdgcn_mfma_f32_32x32x16_bf16(vf[c2],   pb[c2], o0, 0,0,0);
            o1 = __builtin_amdgcn_mfma_f32_32x32x16_bf16(vf[4+c2], pb[c2], o1, 0,0,0);
        }

        asm volatile("s_waitcnt vmcnt(0)" ::: "memory");  // next tile landed
    }

    // epilogue: O = O^T / l, float4 stores (rounds 10-14 proven)
    const float rinv = 1.0f / l_run;
    float* op = out + (size_t)bh*T_*D_ + (size_t)(i0+col)*D_;
    #pragma unroll
    for (int q4=0;q4<4;++q4){
        float4 a = {o0[4*q4]*rinv, o0[4*q4+1]*rinv, o0[4*q4+2]*rinv, o0[4*q4+3]*rinv};
        *reinterpret_cast<float4*>(op + 8*q4 + 4*hi) = a;
        float4 b = {o1[4*q4]*rinv, o1[4*q4+1]*rinv, o1[4*q4+2]*rinv, o1[4*q4+3]*rinv};
        *reinterpret_cast<float4*>(op + 32 + 8*q4 + 4*hi) = b;
    }
}

extern "C" void kernel_launch(void* const* d_in, const int* in_sizes, int n_in,
                              void* d_out, int out_size, void* d_ws, size_t ws_size,
                              hipStream_t stream) {
    const float* q  = (const float*)d_in[0];
    const float* k  = (const float*)d_in[1];
    const float* v  = (const float*)d_in[2];
    const float* f  = (const float*)d_in[3];
    const float* vm = (const float*)d_in[4];
    const float* hm = (const float*)d_in[5];
    float* out = (float*)d_out;

    const size_t slab = (size_t)BH * T_ * D_;
    ushort* KT = (ushort*)d_ws;
    ushort* VT = KT + slab;

    // fused K+V prep (proven bodies, one launch)
    hipLaunchKernelGGL(prep, dim3(BH, 64), dim3(256), 0, stream, k, v, vm, KT, VT);

    dim3 grid(2048);   // 32 bh x 64 q-waves, heavy-first; 1 wave per block
    dim3 block(64);
    hipLaunchKernelGGL(attn_fwd, grid, block, 0, stream, q, f, hm, KT, VT, out);
}